// Round 1
// baseline (2188.746 us; speedup 1.0000x reference)
//
#include <hip/hip_runtime.h>

typedef __attribute__((ext_vector_type(8))) short bf16x8;
typedef __attribute__((ext_vector_type(4))) float fx4;
typedef __attribute__((ext_vector_type(4))) unsigned short u16x4;
typedef __attribute__((ext_vector_type(4))) unsigned int u32x4;

#define DEV static __device__ __forceinline__

DEV unsigned short f2bf(float f) {
  union { float f; unsigned u; } v; v.f = f;
  unsigned u = v.u;
  u += 0x7fffu + ((u >> 16) & 1u);
  return (unsigned short)(u >> 16);
}

DEV float sigm(float x) { return 1.f / (1.f + __expf(-x)); }

// ---------- fp32 -> bf16 elementwise (grid-stride, 4/thread) ----------
__global__ void k_f2bf4(const float* __restrict__ s, unsigned short* __restrict__ d, long n4) {
  long i = (long)blockIdx.x * blockDim.x + threadIdx.x;
  long st = (long)gridDim.x * blockDim.x;
  for (; i < n4; i += st) {
    fx4 v = ((const fx4*)s)[i];
    u16x4 o = { f2bf(v[0]), f2bf(v[1]), f2bf(v[2]), f2bf(v[3]) };
    ((u16x4*)d)[i] = o;
  }
}

// ---------- gather embedding row -> bf16, dst row r = t*32 + b ----------
__global__ void k_gather(const float* __restrict__ emb, const int* __restrict__ tok,
                         unsigned short* __restrict__ dst) {
  int r = blockIdx.x;
  int t = r >> 5, b = r & 31;
  int token = tok[b * 64 + t];  // tok is [B=32][T=64]
  const fx4* srow = (const fx4*)(emb + (long)token * 1024);
  u16x4* drow = (u16x4*)(dst + (long)r * 1024);
  fx4 v = srow[threadIdx.x];
  u16x4 o = { f2bf(v[0]), f2bf(v[1]), f2bf(v[2]), f2bf(v[3]) };
  drow[threadIdx.x] = o;
}

// ---------- per-batch last valid timestep ----------
__global__ void k_lengths(const int* __restrict__ mask, int* __restrict__ sel) {
  int b = threadIdx.x;
  if (b < 32) {
    int s = 0;
    for (int t = 0; t < 64; ++t) s += mask[b * 64 + t];
    sel[b] = (s + 63) & 63;  // (sum-1) with jnp negative-index wrap
  }
}

// ---------- init recurrent state (h -> bf16 dbuf0, c copy) ----------
__global__ void k_init_state(const float* __restrict__ h, const float* __restrict__ c,
                             unsigned short* __restrict__ hbuf0, float* __restrict__ cbuf) {
  int i = blockIdx.x * 256 + threadIdx.x;  // 32768 total
  hbuf0[i] = f2bf(h[i]);
  cbuf[i] = c[i];
}

// ---------- pre-gate GEMM: C[r=(t,b)][n] = sum_k A[r][k]*W[n][k] + bias[n] ----------
// A [2048][1024] bf16, W [4096][1024] bf16, C [2048][4096] fp32.
// grid (64 n-tiles, 64 m-tiles), block 256 (4 waves). Wave w owns n-subtile w*16, both m-halves.
__global__ __launch_bounds__(256) void k_pregate(const unsigned short* __restrict__ A,
                                                 const unsigned short* __restrict__ W,
                                                 const float* __restrict__ bias,
                                                 float* __restrict__ C) {
  int lane = threadIdx.x & 63, w = threadIdx.x >> 6;
  int n0 = blockIdx.x * 64 + w * 16;
  int m0 = blockIdx.y * 32;
  int col = lane & 15, g = lane >> 4;
  fx4 acc0 = {0.f, 0.f, 0.f, 0.f}, acc1 = {0.f, 0.f, 0.f, 0.f};
  const bf16x8* Ar0 = (const bf16x8*)(A + (long)(m0 + col) * 1024);
  const bf16x8* Ar1 = (const bf16x8*)(A + (long)(m0 + 16 + col) * 1024);
  const bf16x8* Br  = (const bf16x8*)(W + (long)(n0 + col) * 1024);
#pragma unroll 4
  for (int kt = 0; kt < 32; ++kt) {
    int kg = kt * 4 + g;  // 8-elem k-group, k = kg*8
    bf16x8 a0 = Ar0[kg];
    bf16x8 a1 = Ar1[kg];
    bf16x8 bb = Br[kg];
    acc0 = __builtin_amdgcn_mfma_f32_16x16x32_bf16(a0, bb, acc0, 0, 0, 0);
    acc1 = __builtin_amdgcn_mfma_f32_16x16x32_bf16(a1, bb, acc1, 0, 0, 0);
  }
  int n = n0 + col;
  float bs = bias[n];
#pragma unroll
  for (int q = 0; q < 4; ++q) {
    C[(long)(m0 + g * 4 + q) * 4096 + n] = acc0[q] + bs;
    C[(long)(m0 + 16 + g * 4 + q) * 4096 + n] = acc1[q] + bs;
  }
}

// ---------- one LSTM timestep ----------
// grid 128 = (j-tile 0..63) x (m-half 0..1), block 256 (4 waves; wave w = gate w).
// MODE 0 = encoder (save h,c at t==sel[b]); MODE 1 = decoder (emit hiddens fp32 + bf16).
template<int MODE>
__global__ __launch_bounds__(256) void k_lstm_step(
    const unsigned short* __restrict__ Whh,   // [4096][1024] bf16
    const float* __restrict__ bhh,            // [4096]
    const float* __restrict__ xg,             // [64][32][4096] fp32
    unsigned short* __restrict__ hbuf,        // [2][32][1024] bf16
    float* __restrict__ cbuf,                 // [32][1024] fp32
    int t,
    const int* __restrict__ sel,
    float* __restrict__ hsel, float* __restrict__ csel,
    float* __restrict__ hid_out,              // [32][64][1024] fp32 (d_out hiddens)
    unsigned short* __restrict__ hid_bf) {    // [2048][1024] bf16, row b*64+t
  int lane = threadIdx.x & 63, w = threadIdx.x >> 6;
  int jt = blockIdx.x >> 1, mh = blockIdx.x & 1;
  int j0 = jt * 16, b0 = mh * 16;
  const unsigned short* hcur = hbuf + (t & 1) * 32768;
  unsigned short* hnxt = hbuf + ((t + 1) & 1) * 32768;
  int col = lane & 15, g = lane >> 4;
  fx4 acc = {0.f, 0.f, 0.f, 0.f};
  const bf16x8* Ar = (const bf16x8*)(hcur + (long)(b0 + col) * 1024);
  const bf16x8* Br = (const bf16x8*)(Whh + (long)(w * 1024 + j0 + col) * 1024);
#pragma unroll 4
  for (int kt = 0; kt < 32; ++kt) {
    int kg = kt * 4 + g;
    bf16x8 a = Ar[kg];
    bf16x8 bb = Br[kg];
    acc = __builtin_amdgcn_mfma_f32_16x16x32_bf16(a, bb, acc, 0, 0, 0);
  }
  __shared__ float gbuf[4][16][16];
  int n = w * 1024 + j0 + col;
  float bb = bhh[n];
  const float* xrow = xg + (long)t * 131072;
#pragma unroll
  for (int q = 0; q < 4; ++q) {
    int bl = g * 4 + q;
    gbuf[w][bl][col] = acc[q] + xrow[(long)(b0 + bl) * 4096 + n] + bb;
  }
  __syncthreads();
  int tid = threadIdx.x;
  int bl = tid >> 4, jl = tid & 15;
  float gi = gbuf[0][bl][jl], gf = gbuf[1][bl][jl];
  float gg = gbuf[2][bl][jl], go = gbuf[3][bl][jl];
  int b = b0 + bl, j = j0 + jl;
  long cidx = (long)b * 1024 + j;
  float c_old = cbuf[cidx];
  float c_new = sigm(gf) * c_old + sigm(gi) * tanhf(gg);
  float h = sigm(go) * tanhf(c_new);
  cbuf[cidx] = c_new;
  hnxt[cidx] = f2bf(h);
  if (MODE == 0) {
    if (t == sel[b]) { hsel[cidx] = h; csel[cidx] = c_new; }
  } else {
    long o = ((long)b * 64 + t) * 1024 + j;
    hid_out[o] = h;
    if (hid_bf) hid_bf[o] = f2bf(h);
  }
}

// ---------- logits GEMM: C[r][n] = sum_k A[r][k]*W[n][k] + bias[n] ----------
// M=2048, N=32000, K=1024. BM=BN=128, BK=32, 4 waves each 64x64. Reg-staged dbuf LDS.
DEV bf16x8 ldsFrag(const unsigned short* p) { return *(const bf16x8*)p; }
DEV bf16x8 ldsFrag(const float* p) {
  bf16x8 r;
#pragma unroll
  for (int j = 0; j < 8; ++j) r[j] = (short)f2bf(p[j]);
  return r;
}

template<typename T>
__global__ __launch_bounds__(256) void k_logits_gemm(const T* __restrict__ A,
                                                     const T* __restrict__ Bw,
                                                     const float* __restrict__ bias,
                                                     float* __restrict__ C) {
  constexpr int EPR = 16 / sizeof(T);        // elems per 16B chunk
  constexpr int CPR = 32 / EPR;              // chunks per 32-elem row
  constexpr int CH  = (128 * CPR) / 256;     // chunks per thread per tile
  __shared__ __align__(16) T As[2][128 * 32];
  __shared__ __align__(16) T Bs[2][128 * 32];
  int tid = threadIdx.x, lane = tid & 63, w = tid >> 6;
  long m0 = (long)blockIdx.y * 128, n0 = (long)blockIdx.x * 128;
  int mw = (w & 1) * 64, nw = (w >> 1) * 64;
  int fr = lane & 15, fg = lane >> 4;
  fx4 acc[4][4] = {};

  u32x4 ra[CH], rb[CH];
  int crow[CH], coff[CH];
#pragma unroll
  for (int u = 0; u < CH; ++u) {
    int c = tid + u * 256;
    crow[u] = c / CPR;
    coff[u] = (c % CPR) * EPR;
  }
  auto loadRegs = [&](int kt) {
    int k0 = kt * 32;
#pragma unroll
    for (int u = 0; u < CH; ++u) {
      ra[u] = *(const u32x4*)(A  + (m0 + crow[u]) * 1024 + k0 + coff[u]);
      rb[u] = *(const u32x4*)(Bw + (n0 + crow[u]) * 1024 + k0 + coff[u]);
    }
  };
  auto storeRegs = [&](int buf) {
#pragma unroll
    for (int u = 0; u < CH; ++u) {
      *(u32x4*)(&As[buf][crow[u] * 32 + coff[u]]) = ra[u];
      *(u32x4*)(&Bs[buf][crow[u] * 32 + coff[u]]) = rb[u];
    }
  };
  loadRegs(0);
  storeRegs(0);
  __syncthreads();
  for (int kt = 0; kt < 32; ++kt) {
    int cur = kt & 1;
    if (kt < 31) loadRegs(kt + 1);
    bf16x8 af[4], bf_[4];
#pragma unroll
    for (int mi = 0; mi < 4; ++mi) af[mi]  = ldsFrag(&As[cur][(mw + mi * 16 + fr) * 32 + fg * 8]);
#pragma unroll
    for (int ni = 0; ni < 4; ++ni) bf_[ni] = ldsFrag(&Bs[cur][(nw + ni * 16 + fr) * 32 + fg * 8]);
#pragma unroll
    for (int mi = 0; mi < 4; ++mi)
#pragma unroll
      for (int ni = 0; ni < 4; ++ni)
        acc[mi][ni] = __builtin_amdgcn_mfma_f32_16x16x32_bf16(af[mi], bf_[ni], acc[mi][ni], 0, 0, 0);
    if (kt < 31) storeRegs((kt + 1) & 1);
    __syncthreads();
  }
#pragma unroll
  for (int ni = 0; ni < 4; ++ni) {
    long n = n0 + nw + ni * 16 + fr;
    float bs = bias[n];
#pragma unroll
    for (int mi = 0; mi < 4; ++mi) {
      long rbase = m0 + mw + mi * 16 + fg * 4;
#pragma unroll
      for (int q = 0; q < 4; ++q)
        C[(rbase + q) * 32000 + n] = acc[mi][ni][q] + bs;
    }
  }
}

// ---------- in-place row log-softmax, V = 32000, one block per row ----------
__global__ __launch_bounds__(256) void k_logsoftmax(float* __restrict__ logits) {
  long base = (long)blockIdx.x * 32000;
  float* row = logits + base;
  int tid = threadIdx.x;
  __shared__ float red[4];
  float m = -3.4e38f;
  for (int i = tid; i < 8000; i += 256) {
    fx4 v = ((const fx4*)row)[i];
    m = fmaxf(m, fmaxf(fmaxf(v[0], v[1]), fmaxf(v[2], v[3])));
  }
  for (int o = 32; o; o >>= 1) m = fmaxf(m, __shfl_xor(m, o));
  if ((tid & 63) == 0) red[tid >> 6] = m;
  __syncthreads();
  m = fmaxf(fmaxf(red[0], red[1]), fmaxf(red[2], red[3]));
  float s = 0.f;
  for (int i = tid; i < 8000; i += 256) {
    fx4 v = ((const fx4*)row)[i];
    s += __expf(v[0] - m) + __expf(v[1] - m) + __expf(v[2] - m) + __expf(v[3] - m);
  }
  for (int o = 32; o; o >>= 1) s += __shfl_xor(s, o);
  __syncthreads();
  if ((tid & 63) == 0) red[tid >> 6] = s;
  __syncthreads();
  float lse = m + logf(red[0] + red[1] + red[2] + red[3]);
  for (int i = tid; i < 8000; i += 256) {
    fx4 v = ((const fx4*)row)[i];
    fx4 o = { v[0] - lse, v[1] - lse, v[2] - lse, v[3] - lse };
    ((fx4*)row)[i] = o;
  }
}

extern "C" void kernel_launch(void* const* d_in, const int* in_sizes, int n_in,
                              void* d_out, int out_size, void* d_ws, size_t ws_size,
                              hipStream_t stream) {
  const int*   x     = (const int*)d_in[0];
  const int*   xmask = (const int*)d_in[1];
  const int*   y     = (const int*)d_in[2];
  const float* h0    = (const float*)d_in[3];
  const float* c0    = (const float*)d_in[4];
  const float* embE  = (const float*)d_in[5];
  const float* embC  = (const float*)d_in[6];
  const float* WihE  = (const float*)d_in[7];
  const float* WhhE  = (const float*)d_in[8];
  const float* bihE  = (const float*)d_in[9];
  const float* bhhE  = (const float*)d_in[10];
  const float* WihD  = (const float*)d_in[11];
  const float* WhhD  = (const float*)d_in[12];
  const float* bihD  = (const float*)d_in[13];
  const float* bhhD  = (const float*)d_in[14];
  const float* Wout  = (const float*)d_in[15];
  const float* bout  = (const float*)d_in[16];

  float* out = (float*)d_out;
  float* decoded = out;                 // [2048][32000] final log-softmax
  float* hiddens = out + 65536000L;     // [32][64][1024] final hiddens

  // Pre-logits scratch lives INSIDE the decoded region (overwritten by the
  // logits GEMM only after all consumers are done).
  float* xg_e = decoded;                          // 8,388,608 floats
  float* xg_d = decoded + 8388608L;
  unsigned short* bfarea  = (unsigned short*)(decoded + 16777216L);
  unsigned short* xe_bf   = bfarea;               // 2,097,152 elems
  unsigned short* ye_bf   = xe_bf + 2097152L;
  unsigned short* WihE_bf = ye_bf + 2097152L;     // 4,194,304 elems each
  unsigned short* WihD_bf = WihE_bf + 4194304L;
  unsigned short* WhhE_bf = WihD_bf + 4194304L;
  unsigned short* WhhD_bf = WhhE_bf + 4194304L;

  // ws layout (small state first, big optional bf16 Wout last)
  char* wp = (char*)d_ws;
  unsigned short* hbuf = (unsigned short*)wp; wp += 2 * 32 * 1024 * 2;
  float* cbuf = (float*)wp; wp += 32 * 1024 * 4;
  float* hsel = (float*)wp; wp += 32 * 1024 * 4;
  float* csel = (float*)wp; wp += 32 * 1024 * 4;
  int* sel = (int*)wp; wp += 256;
  unsigned short* hid_bf  = (unsigned short*)wp; wp += 2048L * 1024 * 2;
  unsigned short* Wout_bf = (unsigned short*)wp; wp += 32000L * 1024 * 2;
  bool fast = ws_size >= (size_t)(wp - (char*)d_ws);

  // weight converts
  k_f2bf4<<<1024, 256, 0, stream>>>(WihE, WihE_bf, 4096L * 1024 / 4);
  k_f2bf4<<<1024, 256, 0, stream>>>(WihD, WihD_bf, 4096L * 1024 / 4);
  k_f2bf4<<<1024, 256, 0, stream>>>(WhhE, WhhE_bf, 4096L * 1024 / 4);
  k_f2bf4<<<1024, 256, 0, stream>>>(WhhD, WhhD_bf, 4096L * 1024 / 4);
  if (fast) k_f2bf4<<<4096, 256, 0, stream>>>(Wout, Wout_bf, 32000L * 1024 / 4);

  // gathers + lengths
  k_gather<<<2048, 256, 0, stream>>>(embE, x, xe_bf);
  k_gather<<<2048, 256, 0, stream>>>(embC, y, ye_bf);
  k_lengths<<<1, 32, 0, stream>>>(xmask, sel);

  // pre-gate GEMMs
  dim3 pg(64, 64);
  k_pregate<<<pg, 256, 0, stream>>>(xe_bf, WihE_bf, bihE, xg_e);
  k_pregate<<<pg, 256, 0, stream>>>(ye_bf, WihD_bf, bihD, xg_d);

  // encoder scan
  k_init_state<<<128, 256, 0, stream>>>(h0, c0, hbuf, cbuf);
  for (int t = 0; t < 64; ++t)
    k_lstm_step<0><<<128, 256, 0, stream>>>(WhhE_bf, bhhE, xg_e, hbuf, cbuf, t,
                                            sel, hsel, csel, nullptr, nullptr);
  // decoder scan
  k_init_state<<<128, 256, 0, stream>>>(hsel, csel, hbuf, cbuf);
  for (int t = 0; t < 64; ++t)
    k_lstm_step<1><<<128, 256, 0, stream>>>(WhhD_bf, bhhD, xg_d, hbuf, cbuf, t,
                                            nullptr, nullptr, nullptr, hiddens,
                                            fast ? hid_bf : nullptr);

  // logits GEMM + log-softmax (in place in d_out)
  dim3 lg(250, 16);
  if (fast) k_logits_gemm<unsigned short><<<lg, 256, 0, stream>>>(hid_bf, Wout_bf, bout, decoded);
  else      k_logits_gemm<float><<<lg, 256, 0, stream>>>(hiddens, Wout, bout, decoded);
  k_logsoftmax<<<2048, 256, 0, stream>>>(decoded);
}